// Round 2
// baseline (105.959 us; speedup 1.0000x reference)
//
#include <hip/hip_runtime.h>
#include <hip/hip_bf16.h>
#include <math.h>

#define NB 16
#define NG 32
#define NM 320
#define NN 960      // 3 * NM
#define NA 3
#define NCH 85
#define NC 80
#define NK 20

// ---------------- K1: per-candidate prep ----------------
// For each (b, n): gather pred cell, compute pred xyxy box, area, p_obj,
// and S = sum_c softplus(z_c)  (f64 accumulation of f32 terms).
__global__ void k_prep(const float* __restrict__ p0, const float* __restrict__ p1, const float* __restrict__ p2,
                       const int* __restrict__ a0, const int* __restrict__ gj0, const int* __restrict__ gi0,
                       const int* __restrict__ a1, const int* __restrict__ gj1, const int* __restrict__ gi1,
                       const int* __restrict__ a2, const int* __restrict__ gj2, const int* __restrict__ gi2,
                       int* __restrict__ coff, int* __restrict__ clvl,
                       float* __restrict__ pobj, float* __restrict__ parea,
                       float* __restrict__ pbox, double* __restrict__ Ssum)
{
    int i = blockIdx.x * blockDim.x + threadIdx.x;
    if (i >= NB * NN) return;
    int b = i / NN, n = i % NN;
    int lvl = (n < NM) ? 0 : ((n < 2 * NM) ? 1 : 2);
    int m = n - lvl * NM;

    const int* pa = (lvl == 0) ? a0 : ((lvl == 1) ? a1 : a2);
    const int* pj = (lvl == 0) ? gj0 : ((lvl == 1) ? gj1 : gj2);
    const int* pi = (lvl == 0) ? gi0 : ((lvl == 1) ? gi1 : gi2);
    const float* pr = (lvl == 0) ? p0 : ((lvl == 1) ? p1 : p2);
    int h = (lvl == 0) ? 80 : ((lvl == 1) ? 40 : 20);
    float s = (lvl == 0) ? 8.0f : ((lvl == 1) ? 16.0f : 32.0f);

    int aa = pa[b * NM + m];
    int jj = pj[b * NM + m];
    int ii = pi[b * NM + m];
    int off = (((b * NA + aa) * h + jj) * h + ii) * NCH;
    const float* c = pr + off;

    float cx = c[0] * s, cy = c[1] * s, w = c[2] * s, hh = c[3] * s;
    float x1 = cx - w * 0.5f, y1 = cy - hh * 0.5f;
    float x2 = cx + w * 0.5f, y2 = cy + hh * 0.5f;

    float po = c[4];
    double S = 0.0;
    for (int cc = 0; cc < NC; ++cc) {
        float pc = c[5 + cc];
        float y = sqrtf(pc * po);
        float z = logf(y / (1.0f - y));
        float sp = fmaxf(z, 0.0f) + log1pf(expf(-fabsf(z)));
        S += (double)sp;
    }

    coff[i] = off;
    clvl[i] = lvl;
    pobj[i] = po;
    parea[i] = (x2 - x1) * (y2 - y1);
    pbox[i * 4 + 0] = x1;
    pbox[i * 4 + 1] = y1;
    pbox[i * 4 + 2] = x2;
    pbox[i * 4 + 3] = y2;
    Ssum[i] = S;
}

// ---------------- K2: one wave per (b, g) ----------------
// Compute cost & iou row (15 elems/lane), dk = max(trunc(sum top-20 iou),1),
// select dk smallest costs (tie -> lowest n), write match0 + cost (f32 out).
__global__ __launch_bounds__(64) void k_row(
        const float* __restrict__ p0, const float* __restrict__ p1, const float* __restrict__ p2,
        const float* __restrict__ tgt,
        const int* __restrict__ coff, const int* __restrict__ clvl,
        const float* __restrict__ pobj, const float* __restrict__ parea,
        const float* __restrict__ pbox, const double* __restrict__ Ssum,
        float* __restrict__ ocost, unsigned char* __restrict__ match0)
{
    int bg = blockIdx.x;            // bg = b*NG + g
    int b = bg / NG;
    int t = (int)threadIdx.x;

    const float* tg = tgt + bg * 6;
    int cls = (int)tg[1];
    float gcx = tg[2] * 640.0f, gcy = tg[3] * 640.0f;
    float gw = tg[4] * 640.0f, gh = tg[5] * 640.0f;
    float gx1 = gcx - gw * 0.5f, gy1 = gcy - gh * 0.5f;
    float gx2 = gcx + gw * 0.5f, gy2 = gcy + gh * 0.5f;
    float ga = (gx2 - gx1) * (gy2 - gy1);

    float cl[15], io[15];
    for (int j = 0; j < 15; ++j) {
        int n = j * 64 + t;
        int idx = b * NN + n;
        int lvl = clvl[idx];
        const float* pr = (lvl == 0) ? p0 : ((lvl == 1) ? p1 : p2);
        float pc = pr[coff[idx] + 5 + cls];
        float po = pobj[idx];
        float y = sqrtf(pc * po);
        float z = logf(y / (1.0f - y));
        float clsl = (float)(Ssum[idx] - (double)z);

        const float* pb = pbox + idx * 4;
        float lx = fmaxf(gx1, pb[0]), ly = fmaxf(gy1, pb[1]);
        float rx = fminf(gx2, pb[2]), ry = fminf(gy2, pb[3]);
        float wx = fmaxf(rx - lx, 0.0f), wy = fmaxf(ry - ly, 0.0f);
        float inter = wx * wy;
        float iou = inter / (ga + parea[idx] - inter);
        float il = -logf(iou + 1e-5f);
        float cst = clsl + 3.0f * il;

        cl[j] = cst;
        io[j] = iou;
        ocost[bg * NN + n] = cst;
    }

    // ---- dk: sum of top-20 iou (iterative extraction; tie-break by n for unique removal)
    float tio[15];
    for (int j = 0; j < 15; ++j) tio[j] = io[j];
    double ssum = 0.0;
    for (int k = 0; k < NK; ++k) {
        float v = -2.0f; int li = 0;
        for (int j = 0; j < 15; ++j) {
            if (tio[j] > v) { v = tio[j]; li = j; }
        }
        float bv = v; int bn = li * 64 + t;
        for (int o = 32; o >= 1; o >>= 1) {
            float ov = __shfl_xor(bv, o, 64);
            int on = __shfl_xor(bn, o, 64);
            if (ov > bv || (ov == bv && on < bn)) { bv = ov; bn = on; }
        }
        ssum += (double)bv;
        if ((bn & 63) == t) tio[bn >> 6] = -2.0f;
    }
    int dk = (int)((float)ssum);
    if (dk < 1) dk = 1;
    if (dk > NK) dk = NK;

    // ---- select dk smallest costs, tie -> lowest n (stable top_k semantics)
    float tco[15];
    for (int j = 0; j < 15; ++j) tco[j] = cl[j];
    unsigned sel = 0;
    for (int k = 0; k < dk; ++k) {
        float v = INFINITY; int li = -1;
        for (int j = 0; j < 15; ++j) {
            if (tco[j] < v) { v = tco[j]; li = j; }
        }
        int myn = (li >= 0) ? (li * 64 + t) : (1 << 20);
        float bv = v; int bn = myn;
        for (int o = 32; o >= 1; o >>= 1) {
            float ov = __shfl_xor(bv, o, 64);
            int on = __shfl_xor(bn, o, 64);
            if (ov < bv || (ov == bv && on < bn)) { bv = ov; bn = on; }
        }
        if ((bn & 63) == t) { sel |= 1u << (bn >> 6); tco[bn >> 6] = INFINITY; }
    }

    for (int j = 0; j < 15; ++j) {
        int n = j * 64 + t;
        match0[bg * NN + n] = (unsigned char)((sel >> j) & 1u);
    }
}

// ---------------- K3: per (b, n) column resolve + outputs (all f32) ----------------
__global__ void k_resolve(const float* __restrict__ cost, const unsigned char* __restrict__ match0,
                          float* __restrict__ om, float* __restrict__ ofg,
                          float* __restrict__ omg)
{
    int i = blockIdx.x * blockDim.x + threadIdx.x;
    if (i >= NB * NN) return;
    int b = i / NN, n = i % NN;

    int cnt = 0, first = -1;
    unsigned mloc = 0;
    for (int g = 0; g < NG; ++g) {
        int v = match0[(b * NG + g) * NN + n];
        if (v) {
            cnt++;
            mloc |= 1u << g;
            if (first < 0) first = g;
        }
    }

    int mgt;
    int fg;
    if (cnt > 1) {
        float bv = INFINITY; int bgi = 0;
        for (int g = 0; g < NG; ++g) {
            float c = cost[(b * NG + g) * NN + n];
            if (c < bv) { bv = c; bgi = g; }
        }
        mloc = 1u << bgi;
        mgt = bgi;
        fg = 1;
    } else {
        mgt = (first >= 0) ? first : 0;
        fg = (cnt > 0) ? 1 : 0;
    }

    for (int g = 0; g < NG; ++g) {
        om[(b * NG + g) * NN + n] = ((mloc >> g) & 1u) ? 1.0f : 0.0f;
    }
    ofg[b * NN + n] = fg ? 1.0f : 0.0f;
    omg[b * NN + n] = (float)mgt;
}

extern "C" void kernel_launch(void* const* d_in, const int* in_sizes, int n_in,
                              void* d_out, int out_size, void* d_ws, size_t ws_size,
                              hipStream_t stream) {
    // setup_inputs() dict order:
    // 0 pred0, 1 a0, 2 gj0, 3 gi0, 4 anc0,
    // 5 pred1, 6 a1, 7 gj1, 8 gi1, 9 anc1,
    // 10 pred2, 11 a2, 12 gj2, 13 gi2, 14 anc2, 15 targets
    const float* p0 = (const float*)d_in[0];
    const int* a0 = (const int*)d_in[1];
    const int* gj0 = (const int*)d_in[2];
    const int* gi0 = (const int*)d_in[3];
    const float* p1 = (const float*)d_in[5];
    const int* a1 = (const int*)d_in[6];
    const int* gj1 = (const int*)d_in[7];
    const int* gi1 = (const int*)d_in[8];
    const float* p2 = (const float*)d_in[10];
    const int* a2 = (const int*)d_in[11];
    const int* gj2 = (const int*)d_in[12];
    const int* gi2 = (const int*)d_in[13];
    const float* tgt = (const float*)d_in[15];

    // Output layout (ALL float32, concatenated in return order):
    // matching (NB*NG*NN) | fg (NB*NN) | matched_gt (NB*NN) | cost (NB*NG*NN)
    float* o = (float*)d_out;
    float* om = o;
    float* ofg = o + (size_t)NB * NG * NN;
    float* omg = ofg + (size_t)NB * NN;
    float* ocost = omg + (size_t)NB * NN;

    // Workspace carve (8B-aligned first)
    char* w = (char*)d_ws;
    double* Ssum = (double*)w;      w += (size_t)NB * NN * sizeof(double);
    float* pbox = (float*)w;        w += (size_t)NB * NN * 4 * sizeof(float);
    float* pobj = (float*)w;        w += (size_t)NB * NN * sizeof(float);
    float* parea = (float*)w;       w += (size_t)NB * NN * sizeof(float);
    int* coff = (int*)w;            w += (size_t)NB * NN * sizeof(int);
    int* clvl = (int*)w;            w += (size_t)NB * NN * sizeof(int);
    unsigned char* match0 = (unsigned char*)w;  w += (size_t)NB * NG * NN;

    (void)in_sizes; (void)n_in; (void)out_size; (void)ws_size;

    int nPrep = NB * NN;
    k_prep<<<(nPrep + 255) / 256, 256, 0, stream>>>(
        p0, p1, p2, a0, gj0, gi0, a1, gj1, gi1, a2, gj2, gi2,
        coff, clvl, pobj, parea, pbox, Ssum);

    k_row<<<NB * NG, 64, 0, stream>>>(
        p0, p1, p2, tgt, coff, clvl, pobj, parea, pbox, Ssum,
        ocost, match0);

    k_resolve<<<(NB * NN + 255) / 256, 256, 0, stream>>>(
        ocost, match0, om, ofg, omg);
}

// Round 3
// 67.450 us; speedup vs baseline: 1.5709x; 1.5709x over previous
//
#include <hip/hip_runtime.h>
#include <hip/hip_bf16.h>
#include <math.h>

#define NB 16
#define NG 32
#define NM 320
#define NN 960      // 3 * NM
#define NA 3
#define NCH 85
#define NC 80
#define NK 20

// ---------------- K1: per-candidate prep (one WAVE per candidate) ----------------
// Lane l handles classes l and l+64; f64 wave-reduce for S = sum_c softplus(z_c).
__global__ __launch_bounds__(256) void k_prep(
                       const float* __restrict__ p0, const float* __restrict__ p1, const float* __restrict__ p2,
                       const int* __restrict__ a0, const int* __restrict__ gj0, const int* __restrict__ gi0,
                       const int* __restrict__ a1, const int* __restrict__ gj1, const int* __restrict__ gi1,
                       const int* __restrict__ a2, const int* __restrict__ gj2, const int* __restrict__ gi2,
                       int* __restrict__ coff, int* __restrict__ clvl,
                       float* __restrict__ pobj, float* __restrict__ parea,
                       float* __restrict__ pbox, double* __restrict__ Ssum)
{
    int wid = blockIdx.x * 4 + ((int)threadIdx.x >> 6);   // candidate index
    int lane = (int)threadIdx.x & 63;
    if (wid >= NB * NN) return;
    int b = wid / NN, n = wid % NN;
    int lvl = (n < NM) ? 0 : ((n < 2 * NM) ? 1 : 2);
    int m = n - lvl * NM;

    const int* pa = (lvl == 0) ? a0 : ((lvl == 1) ? a1 : a2);
    const int* pj = (lvl == 0) ? gj0 : ((lvl == 1) ? gj1 : gj2);
    const int* pi = (lvl == 0) ? gi0 : ((lvl == 1) ? gi1 : gi2);
    const float* pr = (lvl == 0) ? p0 : ((lvl == 1) ? p1 : p2);
    int h = (lvl == 0) ? 80 : ((lvl == 1) ? 40 : 20);
    float s = (lvl == 0) ? 8.0f : ((lvl == 1) ? 16.0f : 32.0f);

    int aa = pa[b * NM + m];
    int jj = pj[b * NM + m];
    int ii = pi[b * NM + m];
    int off = (((b * NA + aa) * h + jj) * h + ii) * NCH;
    const float* c = pr + off;

    float po = c[4];
    double S = 0.0;
    for (int cc = lane; cc < NC; cc += 64) {
        float pc = c[5 + cc];
        float y = sqrtf(pc * po);
        float z = logf(y / (1.0f - y));
        float sp = fmaxf(z, 0.0f) + log1pf(expf(-fabsf(z)));
        S += (double)sp;
    }
    for (int o = 32; o >= 1; o >>= 1) S += __shfl_xor(S, o, 64);

    if (lane == 0) {
        float cx = c[0] * s, cy = c[1] * s, w = c[2] * s, hh = c[3] * s;
        float x1 = cx - w * 0.5f, y1 = cy - hh * 0.5f;
        float x2 = cx + w * 0.5f, y2 = cy + hh * 0.5f;

        coff[wid] = off;
        clvl[wid] = lvl;
        pobj[wid] = po;
        parea[wid] = (x2 - x1) * (y2 - y1);
        pbox[wid * 4 + 0] = x1;
        pbox[wid * 4 + 1] = y1;
        pbox[wid * 4 + 2] = x2;
        pbox[wid * 4 + 3] = y2;
        Ssum[wid] = S;
    }
}

// ---------------- K2: one wave per (b, g) ----------------
// Compute cost & iou row (15 elems/lane), dk = max(trunc(sum top-20 iou),1),
// select dk smallest costs (tie -> lowest n), write match0 + cost (f32 out).
__global__ __launch_bounds__(64) void k_row(
        const float* __restrict__ p0, const float* __restrict__ p1, const float* __restrict__ p2,
        const float* __restrict__ tgt,
        const int* __restrict__ coff, const int* __restrict__ clvl,
        const float* __restrict__ pobj, const float* __restrict__ parea,
        const float* __restrict__ pbox, const double* __restrict__ Ssum,
        float* __restrict__ ocost, unsigned char* __restrict__ match0)
{
    int bg = blockIdx.x;            // bg = b*NG + g
    int b = bg / NG;
    int t = (int)threadIdx.x;

    const float* tg = tgt + bg * 6;
    int cls = (int)tg[1];
    float gcx = tg[2] * 640.0f, gcy = tg[3] * 640.0f;
    float gw = tg[4] * 640.0f, gh = tg[5] * 640.0f;
    float gx1 = gcx - gw * 0.5f, gy1 = gcy - gh * 0.5f;
    float gx2 = gcx + gw * 0.5f, gy2 = gcy + gh * 0.5f;
    float ga = (gx2 - gx1) * (gy2 - gy1);

    float cl[15], io[15];
    for (int j = 0; j < 15; ++j) {
        int n = j * 64 + t;
        int idx = b * NN + n;
        int lvl = clvl[idx];
        const float* pr = (lvl == 0) ? p0 : ((lvl == 1) ? p1 : p2);
        float pc = pr[coff[idx] + 5 + cls];
        float po = pobj[idx];
        float y = sqrtf(pc * po);
        float z = logf(y / (1.0f - y));
        float clsl = (float)(Ssum[idx] - (double)z);

        const float* pb = pbox + idx * 4;
        float lx = fmaxf(gx1, pb[0]), ly = fmaxf(gy1, pb[1]);
        float rx = fminf(gx2, pb[2]), ry = fminf(gy2, pb[3]);
        float wx = fmaxf(rx - lx, 0.0f), wy = fmaxf(ry - ly, 0.0f);
        float inter = wx * wy;
        float iou = inter / (ga + parea[idx] - inter);
        float il = -logf(iou + 1e-5f);
        float cst = clsl + 3.0f * il;

        cl[j] = cst;
        io[j] = iou;
        ocost[bg * NN + n] = cst;
    }

    // ---- dk: sum of top-20 iou (iterative extraction; tie-break by n for unique removal)
    float tio[15];
    for (int j = 0; j < 15; ++j) tio[j] = io[j];
    double ssum = 0.0;
    for (int k = 0; k < NK; ++k) {
        float v = -2.0f; int li = 0;
        for (int j = 0; j < 15; ++j) {
            if (tio[j] > v) { v = tio[j]; li = j; }
        }
        float bv = v; int bn = li * 64 + t;
        for (int o = 32; o >= 1; o >>= 1) {
            float ov = __shfl_xor(bv, o, 64);
            int on = __shfl_xor(bn, o, 64);
            if (ov > bv || (ov == bv && on < bn)) { bv = ov; bn = on; }
        }
        ssum += (double)bv;
        if ((bn & 63) == t) tio[bn >> 6] = -2.0f;
    }
    int dk = (int)((float)ssum);
    if (dk < 1) dk = 1;
    if (dk > NK) dk = NK;

    // ---- select dk smallest costs, tie -> lowest n (stable top_k semantics)
    float tco[15];
    for (int j = 0; j < 15; ++j) tco[j] = cl[j];
    unsigned sel = 0;
    for (int k = 0; k < dk; ++k) {
        float v = INFINITY; int li = -1;
        for (int j = 0; j < 15; ++j) {
            if (tco[j] < v) { v = tco[j]; li = j; }
        }
        int myn = (li >= 0) ? (li * 64 + t) : (1 << 20);
        float bv = v; int bn = myn;
        for (int o = 32; o >= 1; o >>= 1) {
            float ov = __shfl_xor(bv, o, 64);
            int on = __shfl_xor(bn, o, 64);
            if (ov < bv || (ov == bv && on < bn)) { bv = ov; bn = on; }
        }
        if ((bn & 63) == t) { sel |= 1u << (bn >> 6); tco[bn >> 6] = INFINITY; }
    }

    for (int j = 0; j < 15; ++j) {
        int n = j * 64 + t;
        match0[bg * NN + n] = (unsigned char)((sel >> j) & 1u);
    }
}

// ---------------- K3: per (b, n) column resolve + outputs (all f32) ----------------
__global__ void k_resolve(const float* __restrict__ cost, const unsigned char* __restrict__ match0,
                          float* __restrict__ om, float* __restrict__ ofg,
                          float* __restrict__ omg)
{
    int i = blockIdx.x * blockDim.x + threadIdx.x;
    if (i >= NB * NN) return;
    int b = i / NN, n = i % NN;

    int cnt = 0, first = -1;
    unsigned mloc = 0;
    for (int g = 0; g < NG; ++g) {
        int v = match0[(b * NG + g) * NN + n];
        if (v) {
            cnt++;
            mloc |= 1u << g;
            if (first < 0) first = g;
        }
    }

    int mgt;
    int fg;
    if (cnt > 1) {
        float bv = INFINITY; int bgi = 0;
        for (int g = 0; g < NG; ++g) {
            float c = cost[(b * NG + g) * NN + n];
            if (c < bv) { bv = c; bgi = g; }
        }
        mloc = 1u << bgi;
        mgt = bgi;
        fg = 1;
    } else {
        mgt = (first >= 0) ? first : 0;
        fg = (cnt > 0) ? 1 : 0;
    }

    for (int g = 0; g < NG; ++g) {
        om[(b * NG + g) * NN + n] = ((mloc >> g) & 1u) ? 1.0f : 0.0f;
    }
    ofg[b * NN + n] = fg ? 1.0f : 0.0f;
    omg[b * NN + n] = (float)mgt;
}

extern "C" void kernel_launch(void* const* d_in, const int* in_sizes, int n_in,
                              void* d_out, int out_size, void* d_ws, size_t ws_size,
                              hipStream_t stream) {
    const float* p0 = (const float*)d_in[0];
    const int* a0 = (const int*)d_in[1];
    const int* gj0 = (const int*)d_in[2];
    const int* gi0 = (const int*)d_in[3];
    const float* p1 = (const float*)d_in[5];
    const int* a1 = (const int*)d_in[6];
    const int* gj1 = (const int*)d_in[7];
    const int* gi1 = (const int*)d_in[8];
    const float* p2 = (const float*)d_in[10];
    const int* a2 = (const int*)d_in[11];
    const int* gj2 = (const int*)d_in[12];
    const int* gi2 = (const int*)d_in[13];
    const float* tgt = (const float*)d_in[15];

    // Output layout (ALL float32, concatenated in return order):
    // matching (NB*NG*NN) | fg (NB*NN) | matched_gt (NB*NN) | cost (NB*NG*NN)
    float* o = (float*)d_out;
    float* om = o;
    float* ofg = o + (size_t)NB * NG * NN;
    float* omg = ofg + (size_t)NB * NN;
    float* ocost = omg + (size_t)NB * NN;

    // Workspace carve (8B-aligned first)
    char* w = (char*)d_ws;
    double* Ssum = (double*)w;      w += (size_t)NB * NN * sizeof(double);
    float* pbox = (float*)w;        w += (size_t)NB * NN * 4 * sizeof(float);
    float* pobj = (float*)w;        w += (size_t)NB * NN * sizeof(float);
    float* parea = (float*)w;       w += (size_t)NB * NN * sizeof(float);
    int* coff = (int*)w;            w += (size_t)NB * NN * sizeof(int);
    int* clvl = (int*)w;            w += (size_t)NB * NN * sizeof(int);
    unsigned char* match0 = (unsigned char*)w;  w += (size_t)NB * NG * NN;

    (void)in_sizes; (void)n_in; (void)out_size; (void)ws_size;

    int nWaves = NB * NN;                 // one wave per candidate
    k_prep<<<(nWaves + 3) / 4, 256, 0, stream>>>(
        p0, p1, p2, a0, gj0, gi0, a1, gj1, gi1, a2, gj2, gi2,
        coff, clvl, pobj, parea, pbox, Ssum);

    k_row<<<NB * NG, 64, 0, stream>>>(
        p0, p1, p2, tgt, coff, clvl, pobj, parea, pbox, Ssum,
        ocost, match0);

    k_resolve<<<(NB * NN + 255) / 256, 256, 0, stream>>>(
        ocost, match0, om, ofg, omg);
}

// Round 4
// 38.408 us; speedup vs baseline: 2.7588x; 1.7561x over previous
//
#include <hip/hip_runtime.h>
#include <hip/hip_bf16.h>
#include <math.h>

#define NB 16
#define NG 32
#define NM 320
#define NN 960      // 3 * NM
#define NA 3
#define NCH 85
#define NC 80
#define NK 20

// ---------------- DPP wave-reduce helpers (gfx9 lineage: row_shr + row_bcast) ----------
// 64-bit move via two 32-bit update_dpp. old=self (identity for min/max).
template<int CTRL>
__device__ __forceinline__ unsigned long long dpp_u64_self(unsigned long long x) {
    int lo = (int)(unsigned)(x & 0xFFFFFFFFull);
    int hi = (int)(unsigned)(x >> 32);
    int lo2 = __builtin_amdgcn_update_dpp(lo, lo, CTRL, 0xF, 0xF, false);
    int hi2 = __builtin_amdgcn_update_dpp(hi, hi, CTRL, 0xF, 0xF, false);
    return ((unsigned long long)(unsigned)hi2 << 32) | (unsigned)lo2;
}

// max-reduce of u64 keys; result valid in lane 63
__device__ __forceinline__ unsigned long long dpp_max_u64(unsigned long long x) {
    unsigned long long o;
    o = dpp_u64_self<0x111>(x); x = (o > x) ? o : x;   // row_shr:1
    o = dpp_u64_self<0x112>(x); x = (o > x) ? o : x;   // row_shr:2
    o = dpp_u64_self<0x114>(x); x = (o > x) ? o : x;   // row_shr:4
    o = dpp_u64_self<0x118>(x); x = (o > x) ? o : x;   // row_shr:8
    o = dpp_u64_self<0x142>(x); x = (o > x) ? o : x;   // row_bcast:15
    o = dpp_u64_self<0x143>(x); x = (o > x) ? o : x;   // row_bcast:31
    return x;
}

__device__ __forceinline__ unsigned long long dpp_min_u64(unsigned long long x) {
    unsigned long long o;
    o = dpp_u64_self<0x111>(x); x = (o < x) ? o : x;
    o = dpp_u64_self<0x112>(x); x = (o < x) ? o : x;
    o = dpp_u64_self<0x114>(x); x = (o < x) ? o : x;
    o = dpp_u64_self<0x118>(x); x = (o < x) ? o : x;
    o = dpp_u64_self<0x142>(x); x = (o < x) ? o : x;
    o = dpp_u64_self<0x143>(x); x = (o < x) ? o : x;
    return x;
}

// f64 add-reduce (bound_ctrl=1: invalid lanes contribute +0.0); result valid in lane 63
template<int CTRL>
__device__ __forceinline__ double dpp_f64_zero(double x) {
    long long b = __double_as_longlong(x);
    int lo = (int)(unsigned)((unsigned long long)b & 0xFFFFFFFFull);
    int hi = (int)(unsigned)((unsigned long long)b >> 32);
    int lo2 = __builtin_amdgcn_update_dpp(0, lo, CTRL, 0xF, 0xF, true);
    int hi2 = __builtin_amdgcn_update_dpp(0, hi, CTRL, 0xF, 0xF, true);
    unsigned long long r = ((unsigned long long)(unsigned)hi2 << 32) | (unsigned)lo2;
    return __longlong_as_double((long long)r);
}

__device__ __forceinline__ double dpp_sum_f64(double x) {
    x += dpp_f64_zero<0x111>(x);
    x += dpp_f64_zero<0x112>(x);
    x += dpp_f64_zero<0x114>(x);
    x += dpp_f64_zero<0x118>(x);
    x += dpp_f64_zero<0x142>(x);
    x += dpp_f64_zero<0x143>(x);
    return x;   // lane 63 holds the total
}

// ---------------- K1: per-candidate prep (one WAVE per candidate) ----------------
__global__ __launch_bounds__(256) void k_prep(
                       const float* __restrict__ p0, const float* __restrict__ p1, const float* __restrict__ p2,
                       const int* __restrict__ a0, const int* __restrict__ gj0, const int* __restrict__ gi0,
                       const int* __restrict__ a1, const int* __restrict__ gj1, const int* __restrict__ gi1,
                       const int* __restrict__ a2, const int* __restrict__ gj2, const int* __restrict__ gi2,
                       int* __restrict__ coff, int* __restrict__ clvl,
                       float* __restrict__ pobj, float* __restrict__ parea,
                       float* __restrict__ pbox, double* __restrict__ Ssum)
{
    int wid = blockIdx.x * 4 + ((int)threadIdx.x >> 6);   // candidate index
    int lane = (int)threadIdx.x & 63;
    if (wid >= NB * NN) return;
    int b = wid / NN, n = wid % NN;
    int lvl = (n < NM) ? 0 : ((n < 2 * NM) ? 1 : 2);
    int m = n - lvl * NM;

    const int* pa = (lvl == 0) ? a0 : ((lvl == 1) ? a1 : a2);
    const int* pj = (lvl == 0) ? gj0 : ((lvl == 1) ? gj1 : gj2);
    const int* pi = (lvl == 0) ? gi0 : ((lvl == 1) ? gi1 : gi2);
    const float* pr = (lvl == 0) ? p0 : ((lvl == 1) ? p1 : p2);
    int h = (lvl == 0) ? 80 : ((lvl == 1) ? 40 : 20);
    float s = (lvl == 0) ? 8.0f : ((lvl == 1) ? 16.0f : 32.0f);

    int aa = pa[b * NM + m];
    int jj = pj[b * NM + m];
    int ii = pi[b * NM + m];
    int off = (((b * NA + aa) * h + jj) * h + ii) * NCH;
    const float* c = pr + off;

    float po = c[4];
    double S = 0.0;
    for (int cc = lane; cc < NC; cc += 64) {
        float pc = c[5 + cc];
        float y = sqrtf(pc * po);
        float z = logf(y / (1.0f - y));
        float sp = fmaxf(z, 0.0f) + log1pf(expf(-fabsf(z)));
        S += (double)sp;
    }
    S = dpp_sum_f64(S);   // valid in lane 63

    if (lane == 63) {
        float cx = c[0] * s, cy = c[1] * s, w = c[2] * s, hh = c[3] * s;
        float x1 = cx - w * 0.5f, y1 = cy - hh * 0.5f;
        float x2 = cx + w * 0.5f, y2 = cy + hh * 0.5f;

        coff[wid] = off;
        clvl[wid] = lvl;
        pobj[wid] = po;
        parea[wid] = (x2 - x1) * (y2 - y1);
        pbox[wid * 4 + 0] = x1;
        pbox[wid * 4 + 1] = y1;
        pbox[wid * 4 + 2] = x2;
        pbox[wid * 4 + 3] = y2;
        Ssum[wid] = S;
    }
}

// ---------------- K2: one wave per (b, g) ----------------
__global__ __launch_bounds__(64) void k_row(
        const float* __restrict__ p0, const float* __restrict__ p1, const float* __restrict__ p2,
        const float* __restrict__ tgt,
        const int* __restrict__ coff, const int* __restrict__ clvl,
        const float* __restrict__ pobj, const float* __restrict__ parea,
        const float* __restrict__ pbox, const double* __restrict__ Ssum,
        float* __restrict__ ocost, unsigned char* __restrict__ match0)
{
    int bg = blockIdx.x;            // bg = b*NG + g
    int b = bg / NG;
    int t = (int)threadIdx.x;

    const float* tg = tgt + bg * 6;
    int cls = (int)tg[1];
    float gcx = tg[2] * 640.0f, gcy = tg[3] * 640.0f;
    float gw = tg[4] * 640.0f, gh = tg[5] * 640.0f;
    float gx1 = gcx - gw * 0.5f, gy1 = gcy - gh * 0.5f;
    float gx2 = gcx + gw * 0.5f, gy2 = gcy + gh * 0.5f;
    float ga = (gx2 - gx1) * (gy2 - gy1);

    float cl[15], io[15];
    #pragma unroll
    for (int j = 0; j < 15; ++j) {
        int n = j * 64 + t;
        int idx = b * NN + n;
        int lvl = clvl[idx];
        const float* pr = (lvl == 0) ? p0 : ((lvl == 1) ? p1 : p2);
        float pc = pr[coff[idx] + 5 + cls];
        float po = pobj[idx];
        float y = sqrtf(pc * po);
        float z = logf(y / (1.0f - y));
        float clsl = (float)(Ssum[idx] - (double)z);

        const float* pb = pbox + idx * 4;
        float lx = fmaxf(gx1, pb[0]), ly = fmaxf(gy1, pb[1]);
        float rx = fminf(gx2, pb[2]), ry = fminf(gy2, pb[3]);
        float wx = fmaxf(rx - lx, 0.0f), wy = fmaxf(ry - ly, 0.0f);
        float inter = wx * wy;
        float iou = inter / (ga + parea[idx] - inter);
        float il = -logf(iou + 1e-5f);
        float cst = clsl + 3.0f * il;

        cl[j] = cst;
        io[j] = iou;
        ocost[bg * NN + n] = cst;
    }

    // ---- dk: sum of top-20 iou. iou >= 0, so float bits are order-monotonic.
    // key = (iou_bits << 32) | ~n : max key = max iou, tie -> lowest n.
    double ssum = 0.0;
    for (int k = 0; k < NK; ++k) {
        float bv = io[0]; int bj = 0;
        #pragma unroll
        for (int j = 1; j < 15; ++j) {
            if (io[j] > bv) { bv = io[j]; bj = j; }
        }
        unsigned long long key =
            ((unsigned long long)__float_as_uint(bv) << 32) | (unsigned)(~(unsigned)(bj * 64 + t));
        key = dpp_max_u64(key);
        unsigned lo = (unsigned)__builtin_amdgcn_readlane((int)(unsigned)(key & 0xFFFFFFFFull), 63);
        unsigned hi = (unsigned)__builtin_amdgcn_readlane((int)(unsigned)(key >> 32), 63);
        float mval = __uint_as_float(hi);
        int mn = (int)(~lo);
        ssum += (double)mval;
        bool win = ((mn & 63) == t);
        int slot = mn >> 6;
        #pragma unroll
        for (int j = 0; j < 15; ++j) io[j] = (win && slot == j) ? -2.0f : io[j];
    }
    int dk = (int)((float)ssum);
    if (dk < 1) dk = 1;
    if (dk > NK) dk = NK;

    // ---- select dk smallest costs (cost >> 0 here, bits monotonic), tie -> lowest n.
    // key = (cost_bits << 32) | n : min key = min cost, tie -> lowest n.
    unsigned sel = 0;
    for (int k = 0; k < dk; ++k) {
        float bv = cl[0]; int bj = 0;
        #pragma unroll
        for (int j = 1; j < 15; ++j) {
            if (cl[j] < bv) { bv = cl[j]; bj = j; }
        }
        unsigned long long key =
            ((unsigned long long)__float_as_uint(bv) << 32) | (unsigned)(bj * 64 + t);
        key = dpp_min_u64(key);
        unsigned lo = (unsigned)__builtin_amdgcn_readlane((int)(unsigned)(key & 0xFFFFFFFFull), 63);
        int mn = (int)lo;
        bool win = ((mn & 63) == t);
        int slot = mn >> 6;
        if (win) sel |= 1u << slot;
        #pragma unroll
        for (int j = 0; j < 15; ++j) cl[j] = (win && slot == j) ? INFINITY : cl[j];
    }

    #pragma unroll
    for (int j = 0; j < 15; ++j) {
        int n = j * 64 + t;
        match0[bg * NN + n] = (unsigned char)((sel >> j) & 1u);
    }
}

// ---------------- K3: per (b, n) column resolve + outputs (all f32) ----------------
__global__ void k_resolve(const float* __restrict__ cost, const unsigned char* __restrict__ match0,
                          float* __restrict__ om, float* __restrict__ ofg,
                          float* __restrict__ omg)
{
    int i = blockIdx.x * blockDim.x + threadIdx.x;
    if (i >= NB * NN) return;
    int b = i / NN, n = i % NN;

    int cnt = 0, first = -1;
    unsigned mloc = 0;
    #pragma unroll
    for (int g = 0; g < NG; ++g) {
        int v = match0[(b * NG + g) * NN + n];
        if (v) {
            cnt++;
            mloc |= 1u << g;
            if (first < 0) first = g;
        }
    }

    int mgt;
    int fg;
    if (cnt > 1) {
        float bv = INFINITY; int bgi = 0;
        #pragma unroll
        for (int g = 0; g < NG; ++g) {
            float c = cost[(b * NG + g) * NN + n];
            if (c < bv) { bv = c; bgi = g; }
        }
        mloc = 1u << bgi;
        mgt = bgi;
        fg = 1;
    } else {
        mgt = (first >= 0) ? first : 0;
        fg = (cnt > 0) ? 1 : 0;
    }

    #pragma unroll
    for (int g = 0; g < NG; ++g) {
        om[(b * NG + g) * NN + n] = ((mloc >> g) & 1u) ? 1.0f : 0.0f;
    }
    ofg[b * NN + n] = fg ? 1.0f : 0.0f;
    omg[b * NN + n] = (float)mgt;
}

extern "C" void kernel_launch(void* const* d_in, const int* in_sizes, int n_in,
                              void* d_out, int out_size, void* d_ws, size_t ws_size,
                              hipStream_t stream) {
    const float* p0 = (const float*)d_in[0];
    const int* a0 = (const int*)d_in[1];
    const int* gj0 = (const int*)d_in[2];
    const int* gi0 = (const int*)d_in[3];
    const float* p1 = (const float*)d_in[5];
    const int* a1 = (const int*)d_in[6];
    const int* gj1 = (const int*)d_in[7];
    const int* gi1 = (const int*)d_in[8];
    const float* p2 = (const float*)d_in[10];
    const int* a2 = (const int*)d_in[11];
    const int* gj2 = (const int*)d_in[12];
    const int* gi2 = (const int*)d_in[13];
    const float* tgt = (const float*)d_in[15];

    // Output layout (ALL float32, concatenated in return order):
    // matching (NB*NG*NN) | fg (NB*NN) | matched_gt (NB*NN) | cost (NB*NG*NN)
    float* o = (float*)d_out;
    float* om = o;
    float* ofg = o + (size_t)NB * NG * NN;
    float* omg = ofg + (size_t)NB * NN;
    float* ocost = omg + (size_t)NB * NN;

    // Workspace carve (8B-aligned first)
    char* w = (char*)d_ws;
    double* Ssum = (double*)w;      w += (size_t)NB * NN * sizeof(double);
    float* pbox = (float*)w;        w += (size_t)NB * NN * 4 * sizeof(float);
    float* pobj = (float*)w;        w += (size_t)NB * NN * sizeof(float);
    float* parea = (float*)w;       w += (size_t)NB * NN * sizeof(float);
    int* coff = (int*)w;            w += (size_t)NB * NN * sizeof(int);
    int* clvl = (int*)w;            w += (size_t)NB * NN * sizeof(int);
    unsigned char* match0 = (unsigned char*)w;  w += (size_t)NB * NG * NN;

    (void)in_sizes; (void)n_in; (void)out_size; (void)ws_size;

    int nWaves = NB * NN;                 // one wave per candidate
    k_prep<<<(nWaves + 3) / 4, 256, 0, stream>>>(
        p0, p1, p2, a0, gj0, gi0, a1, gj1, gi1, a2, gj2, gi2,
        coff, clvl, pobj, parea, pbox, Ssum);

    k_row<<<NB * NG, 64, 0, stream>>>(
        p0, p1, p2, tgt, coff, clvl, pobj, parea, pbox, Ssum,
        ocost, match0);

    k_resolve<<<(NB * NN + 255) / 256, 256, 0, stream>>>(
        ocost, match0, om, ofg, omg);
}